// Round 1
// baseline (64.793 us; speedup 1.0000x reference)
//
#include <hip/hip_runtime.h>
#include <math.h>

#define V 8
#define B 128
#define P 512
#define NE 75

static constexpr float NU = 0.1f;
static constexpr float EPS = 1e-5f;
static constexpr float INV_SQRT2 = 0.70710678118654752440f;
static constexpr float L2E = 1.4426950408889634f;  // log2(e)

__device__ __forceinline__ float fast_exp2(float x) {
#if __has_builtin(__builtin_amdgcn_exp2f)
  return __builtin_amdgcn_exp2f(x);
#else
  return exp2f(x);
#endif
}

// ---------------------------------------------------------------------------
// K1: 45-degree rotate + log-threshold transform, mask folded in.
// Masked-out points get (1e19,1e19) so the Gaussian arg -> -huge -> exp2 -> 0.
// ---------------------------------------------------------------------------
__global__ void k_transform(const float* __restrict__ points,
                            const int* __restrict__ lengths,
                            float2* __restrict__ tp) {
  int idx = blockIdx.x * blockDim.x + threadIdx.x;
  if (idx >= V * B * P) return;
  int p = idx & (P - 1);
  int vb = idx >> 9;  // /P
  float x0 = points[idx * 2 + 0];
  float x1 = points[idx * 2 + 1];
  float s = (x0 + x1) * INV_SQRT2;
  float y = (x1 - x0) * INV_SQRT2;
  if (y <= NU) y = logf(fmaxf(y, 1e-12f) * 10.0f) + NU;
  if (p >= lengths[vb]) { s = 1e19f; y = 1e19f; }
  tp[idx] = make_float2(s, y);
}

// ---------------------------------------------------------------------------
// K2 (hot): sl[i][b][j][n] = sum_p exp(-(a*(s-cs)^2 + c*(y-cy)^2))
// Quadratic expansion, log2e folded into coefficients:
//   arg2 = Bs*s + By*y - A*s2 - C*y2 - D   (all pre-scaled by log2e)
// Block handles one (i,b); threads t<225 map to (j = t/75, n = t%75).
// ---------------------------------------------------------------------------
__global__ __launch_bounds__(256) void k_structure(
    const float2* __restrict__ tp,
    const float* __restrict__ centers,
    const float* __restrict__ sharp,
    float* __restrict__ sl) {
  int i = blockIdx.x >> 7;     // / B
  int b = blockIdx.x & 127;
  int t = threadIdx.x;
  int j = (t >= 150) ? 2 : (t >= 75 ? 1 : 0);
  int n = t - j * 75;
  bool active = (t < 225);
  if (!active) { j = 2; n = 74; }

  // per-center coefficients (uniform over b, cheap to recompute per block)
  int ci = (i * NE + n) * 2;
  float a  = sharp[ci],    c  = sharp[ci + 1];
  float cs = centers[ci],  cy = centers[ci + 1];
  float nA = -a * L2E;
  float nC = -c * L2E;
  float Bs = 2.0f * a * cs * L2E;
  float By = 2.0f * c * cy * L2E;
  float nD = -(a * cs * cs + c * cy * cy) * L2E;

  __shared__ float4 lds[3][128];
  float acc = 0.0f;

  for (int ch = 0; ch < P / 128; ++ch) {
    __syncthreads();
    for (int u = t; u < 384; u += 256) {
      int jj = u >> 7;
      int pp = u & 127;
      int d = (i + jj - 1 + V) & (V - 1);  // source direction, V=8 pow2
      float2 q = tp[((size_t)d * B + b) * P + ch * 128 + pp];
      lds[jj][pp] = make_float4(q.x, q.y, q.x * q.x, q.y * q.y);
    }
    __syncthreads();
#pragma unroll 8
    for (int p = 0; p < 128; ++p) {
      float4 q = lds[j][p];
      float arg = fmaf(Bs, q.x, fmaf(By, q.y, fmaf(nA, q.z, fmaf(nC, q.w, nD))));
      acc += fast_exp2(arg);
    }
  }
  if (active) sl[(((size_t)i * B + b) * 3 + j) * NE + n] = acc;  // coalesced: +t
}

// ---------------------------------------------------------------------------
// K3: conv1d(3->16) -> conv1d(16->4) -> max over channels -> l1 (75->25)
// One block per (i,b), 128 threads (n<75 for convs, k<25 for l1).
// ---------------------------------------------------------------------------
__global__ void k_head(const float* __restrict__ sl,
                       const float* __restrict__ c1w,
                       const float* __restrict__ c2w,
                       const float* __restrict__ l1w,
                       const float* __restrict__ l1b,
                       float* __restrict__ A1) {
  int i = blockIdx.x >> 7;
  int b = blockIdx.x & 127;
  int t = threadIdx.x;
  __shared__ float hn[NE];
  if (t < NE) {
    const float* slp = sl + (((size_t)i * B + b) * 3) * NE + t;
    float s0 = slp[0], s1 = slp[NE], s2 = slp[2 * NE];
    float a0 = 0, a1 = 0, a2 = 0, a3 = 0;
#pragma unroll
    for (int f = 0; f < 16; ++f) {
      float w0 = c1w[(i * 16 + f) * 3 + 0];
      float w1 = c1w[(i * 16 + f) * 3 + 1];
      float w2 = c1w[(i * 16 + f) * 3 + 2];
      float h1 = fmaf(w0, s0, fmaf(w1, s1, w2 * s2));
      a0 = fmaf(c2w[(i * 4 + 0) * 16 + f], h1, a0);
      a1 = fmaf(c2w[(i * 4 + 1) * 16 + f], h1, a1);
      a2 = fmaf(c2w[(i * 4 + 2) * 16 + f], h1, a2);
      a3 = fmaf(c2w[(i * 4 + 3) * 16 + f], h1, a3);
    }
    hn[t] = fmaxf(fmaxf(a0, a1), fmaxf(a2, a3));
  }
  __syncthreads();
  if (t < 25) {
    float acc = l1b[i * 25 + t];
    const float* w = l1w + ((size_t)i * 25 + t) * NE;
#pragma unroll 5
    for (int n = 0; n < NE; ++n) acc = fmaf(w[n], hn[n], acc);
    A1[((size_t)i * B + b) * 25 + t] = acc;
  }
}

// ---------------------------------------------------------------------------
// K4: bn1 batch stats (two-pass for precision). One block, 256 threads.
// mr layout: [0..199]=mean, [200..399]=rstd
// ---------------------------------------------------------------------------
__global__ void k_bn1_stats(const float* __restrict__ A1, float* __restrict__ mr) {
  int t = threadIdx.x;
  if (t >= 200) return;
  int i = t / 25, k = t % 25;
  const float* p = A1 + (size_t)i * B * 25 + k;
  float s = 0;
  for (int b = 0; b < B; ++b) s += p[b * 25];
  float m = s * (1.0f / B);
  float v = 0;
  for (int b = 0; b < B; ++b) { float d = p[b * 25] - m; v = fmaf(d, d, v); }
  v *= (1.0f / B);
  mr[t] = m;
  mr[200 + t] = rsqrtf(v + EPS);
}

// ---------------------------------------------------------------------------
// K5: bn1-apply + l2 (25x25) + relu -> X[b, i*25+k]
// ---------------------------------------------------------------------------
__global__ void k_l2(const float* __restrict__ A1, const float* __restrict__ mr,
                     const float* __restrict__ g1, const float* __restrict__ b1,
                     const float* __restrict__ l2w, const float* __restrict__ l2b,
                     float* __restrict__ X) {
  int i = blockIdx.x >> 7;
  int b = blockIdx.x & 127;
  int t = threadIdx.x;
  __shared__ float xb[25];
  if (t < 25) {
    int ik = i * 25 + t;
    float v = A1[((size_t)i * B + b) * 25 + t];
    xb[t] = (v - mr[ik]) * mr[200 + ik] * g1[ik] + b1[ik];
  }
  __syncthreads();
  if (t < 25) {
    float acc = l2b[i * 25 + t];
    const float* w = l2w + ((size_t)i * 25 + t) * 25;
#pragma unroll
    for (int jj = 0; jj < 25; ++jj) acc = fmaf(w[jj], xb[jj], acc);
    X[(size_t)b * 200 + i * 25 + t] = fmaxf(acc, 0.0f);
  }
}

// ---------------------------------------------------------------------------
// K6: fc1 [B,200]@[200,100]^T
// ---------------------------------------------------------------------------
__global__ void k_fc1(const float* __restrict__ X, const float* __restrict__ w,
                      const float* __restrict__ bias, float* __restrict__ Y) {
  int b = blockIdx.x;
  int t = threadIdx.x;
  __shared__ float xr[200];
  for (int q = t; q < 200; q += 128) xr[q] = X[(size_t)b * 200 + q];
  __syncthreads();
  if (t < 100) {
    float acc = bias[t];
    const float* wp = w + (size_t)t * 200;
#pragma unroll 8
    for (int q = 0; q < 200; ++q) acc = fmaf(wp[q], xr[q], acc);
    Y[(size_t)b * 100 + t] = acc;
  }
}

// ---------------------------------------------------------------------------
// K7: fc1 bn stats. One block, 128 threads. mr2: [0..99]=mean,[100..199]=rstd
// ---------------------------------------------------------------------------
__global__ void k_bn2_stats(const float* __restrict__ Y, float* __restrict__ mr2) {
  int t = threadIdx.x;
  if (t >= 100) return;
  const float* p = Y + t;
  float s = 0;
  for (int b = 0; b < B; ++b) s += p[b * 100];
  float m = s * (1.0f / B);
  float v = 0;
  for (int b = 0; b < B; ++b) { float d = p[b * 100] - m; v = fmaf(d, d, v); }
  v *= (1.0f / B);
  mr2[t] = m;
  mr2[100 + t] = rsqrtf(v + EPS);
}

// ---------------------------------------------------------------------------
// K8: bn2-apply + fc2 -> out[B,70]
// ---------------------------------------------------------------------------
__global__ void k_fc2(const float* __restrict__ Y, const float* __restrict__ mr2,
                      const float* __restrict__ g2, const float* __restrict__ b2,
                      const float* __restrict__ w, const float* __restrict__ bias,
                      float* __restrict__ out) {
  int b = blockIdx.x;
  int t = threadIdx.x;
  __shared__ float yr[100];
  if (t < 100) {
    float v = Y[(size_t)b * 100 + t];
    yr[t] = (v - mr2[t]) * mr2[100 + t] * g2[t] + b2[t];
  }
  __syncthreads();
  if (t < 70) {
    float acc = bias[t];
    const float* wp = w + (size_t)t * 100;
#pragma unroll 4
    for (int m = 0; m < 100; ++m) acc = fmaf(wp[m], yr[m], acc);
    out[(size_t)b * 70 + t] = acc;
  }
}

// ---------------------------------------------------------------------------
extern "C" void kernel_launch(void* const* d_in, const int* in_sizes, int n_in,
                              void* d_out, int out_size, void* d_ws, size_t ws_size,
                              hipStream_t stream) {
  const float* points  = (const float*)d_in[0];
  const int*   lengths = (const int*)d_in[1];
  const float* centers = (const float*)d_in[2];
  const float* sharp   = (const float*)d_in[3];
  const float* c1w     = (const float*)d_in[4];
  const float* c2w     = (const float*)d_in[5];
  const float* l1w     = (const float*)d_in[6];
  const float* l1b     = (const float*)d_in[7];
  const float* bn1g    = (const float*)d_in[8];
  const float* bn1b    = (const float*)d_in[9];
  const float* l2w     = (const float*)d_in[10];
  const float* l2b     = (const float*)d_in[11];
  const float* fc1w    = (const float*)d_in[12];
  const float* fc1b    = (const float*)d_in[13];
  const float* fbn_g   = (const float*)d_in[14];
  const float* fbn_b   = (const float*)d_in[15];
  const float* fc2w    = (const float*)d_in[16];
  const float* fc2b    = (const float*)d_in[17];
  float* out = (float*)d_out;

  char* ws = (char*)d_ws;
  float2* tp = (float2*)ws;                               // V*B*P float2 = 4 MB
  float*  sl  = (float*)(ws + (size_t)V * B * P * 8);     // V*B*3*NE
  float*  A1  = sl + (size_t)V * B * 3 * NE;              // V*B*25
  float*  mr1 = A1 + (size_t)V * B * 25;                  // 400
  float*  X   = mr1 + 400;                                // B*200
  float*  Y   = X + (size_t)B * 200;                      // B*100
  float*  mr2 = Y + (size_t)B * 100;                      // 200

  k_transform<<<dim3((V * B * P + 255) / 256), dim3(256), 0, stream>>>(points, lengths, tp);
  k_structure<<<dim3(V * B), dim3(256), 0, stream>>>(tp, centers, sharp, sl);
  k_head<<<dim3(V * B), dim3(128), 0, stream>>>(sl, c1w, c2w, l1w, l1b, A1);
  k_bn1_stats<<<dim3(1), dim3(256), 0, stream>>>(A1, mr1);
  k_l2<<<dim3(V * B), dim3(64), 0, stream>>>(A1, mr1, bn1g, bn1b, l2w, l2b, X);
  k_fc1<<<dim3(B), dim3(128), 0, stream>>>(X, fc1w, fc1b, Y);
  k_bn2_stats<<<dim3(1), dim3(128), 0, stream>>>(Y, mr2);
  k_fc2<<<dim3(B), dim3(128), 0, stream>>>(Y, mr2, fbn_g, fbn_b, fc2w, fc2b, out);
}

// Round 2
// 45.920 us; speedup vs baseline: 1.4110x; 1.4110x over previous
//
#include <hip/hip_runtime.h>
#include <math.h>

#define V 8
#define B 128
#define P 512
#define NE 75

static constexpr float NU = 0.1f;
static constexpr float EPS = 1e-5f;
static constexpr float INV_SQRT2 = 0.70710678118654752440f;
static constexpr float L2E = 1.4426950408889634f;  // log2(e)

typedef float v2f __attribute__((ext_vector_type(2)));

__device__ __forceinline__ float fast_exp2(float x) {
#if __has_builtin(__builtin_amdgcn_exp2f)
  return __builtin_amdgcn_exp2f(x);
#else
  return exp2f(x);
#endif
}

__device__ __forceinline__ v2f v2fma(v2f a, v2f b, v2f c) {
#if __has_builtin(__builtin_elementwise_fma)
  return __builtin_elementwise_fma(a, b, c);
#else
  v2f r;
  r.x = fmaf(a.x, b.x, c.x);
  r.y = fmaf(a.y, b.y, c.y);
  return r;
#endif
}

// ---------------------------------------------------------------------------
// KA (hot, fused): transform + masked Gaussian structure sums + conv1d(3->16)
//                  -> conv1d(16->4) -> channel-max -> l1(75->25)
// One block per (i,b), 256 threads. Output A1t layout [i*25+k][b] (column-
// contiguous over b) so the tail's batch stats are coalesced float4 reads.
//
// Hot loop: per-lane trip count = roundup4(len of my direction). Wave cost =
// wave-max length (~63% of 512 on average). Masked points staged as 1e9 so
// arg -> -5.8e18 -> exp2 -> 0 exactly (no overflow to NaN: all terms finite
// or -huge, never +inf).
// ---------------------------------------------------------------------------
__global__ __launch_bounds__(256, 4) void k_structure(
    const float2* __restrict__ pts2,      // [V,B,P] float2 (birth,death)
    const int* __restrict__ lengths,      // [V,B]
    const float* __restrict__ centers,    // [V,NE,2] (already transformed)
    const float* __restrict__ sharp,      // [V,NE,2]
    const float* __restrict__ c1w,        // [V,16,3]
    const float* __restrict__ c2w,        // [V,4,16]
    const float* __restrict__ l1w,        // [V,25,NE]
    const float* __restrict__ l1b,        // [V,25]
    float* __restrict__ A1t) {            // [V*25][B]
  int i = blockIdx.x >> 7;
  int b = blockIdx.x & 127;
  int t = threadIdx.x;

  __shared__ float sS[3][P], sY[3][P], sS2[3][P], sY2[3][P];  // 24 KB SoA
  __shared__ float slb[3][NE];
  __shared__ float hn[NE];

  // ---- staging: load+transform all 3 neighbor directions (1536 points) ----
  for (int u = t; u < 3 * P; u += 256) {
    int jj = u >> 9;          // /P
    int pp = u & (P - 1);
    int d = (i + jj - 1 + V) & (V - 1);
    int len = lengths[d * B + b];
    float2 q = pts2[((size_t)d * B + b) * P + pp];
    float s = (q.x + q.y) * INV_SQRT2;
    float y = (q.y - q.x) * INV_SQRT2;
    if (y <= NU) y = __logf(fmaxf(y, 1e-12f) * 10.0f) + NU;
    if (pp >= len) { s = 1e9f; y = 1e9f; }
    sS[jj][pp] = s;
    sY[jj][pp] = y;
    sS2[jj][pp] = s * s;
    sY2[jj][pp] = y * y;
  }

  // ---- per-thread (j,n) mapping: 225 active lanes, dummies do harmless work
  int j = (t >= 150) ? 2 : (t >= 75 ? 1 : 0);
  int n = t - j * 75;
  bool active = (t < 225);
  if (!active) { j = 2; n = 74; }

  int ci = (i * NE + n) * 2;
  float a  = sharp[ci],   c  = sharp[ci + 1];
  float cs = centers[ci], cy = centers[ci + 1];
  float nA = -a * L2E;
  float nC = -c * L2E;
  float Bsc = 2.0f * a * cs * L2E;
  float Byc = 2.0f * c * cy * L2E;
  float nD = -(a * cs * cs + c * cy * cy) * L2E;
  v2f nA2 = {nA, nA}, nC2 = {nC, nC}, Bs2 = {Bsc, Bsc}, By2 = {Byc, Byc},
      nD2 = {nD, nD};

  int mylen = lengths[(((i + j - 1 + V) & (V - 1)) * B) + b];
  int bound = (mylen + 3) & ~3;  // step 4 points/iter

  __syncthreads();

  float acc0 = 0.f, acc1 = 0.f, acc2 = 0.f, acc3 = 0.f;
  for (int p = 0; p < bound; p += 4) {
    v2f sa = *(const v2f*)&sS[j][p],  sb = *(const v2f*)&sS[j][p + 2];
    v2f ya = *(const v2f*)&sY[j][p],  yb = *(const v2f*)&sY[j][p + 2];
    v2f qa = *(const v2f*)&sS2[j][p], qb = *(const v2f*)&sS2[j][p + 2];
    v2f ra = *(const v2f*)&sY2[j][p], rb = *(const v2f*)&sY2[j][p + 2];
    v2f arga = v2fma(qa, nA2, v2fma(ra, nC2, v2fma(sa, Bs2, v2fma(ya, By2, nD2))));
    v2f argb = v2fma(qb, nA2, v2fma(rb, nC2, v2fma(sb, Bs2, v2fma(yb, By2, nD2))));
    acc0 += fast_exp2(arga.x);
    acc1 += fast_exp2(arga.y);
    acc2 += fast_exp2(argb.x);
    acc3 += fast_exp2(argb.y);
  }
  float accv = (acc0 + acc1) + (acc2 + acc3);

  if (active) slb[j][n] = accv;
  __syncthreads();

  // ---- head: conv1(3->16) -> conv2(16->4) -> max -> stored in hn[n] ----
  if (t < NE) {
    float s0 = slb[0][t], s1 = slb[1][t], s2 = slb[2][t];
    float a0 = 0, a1 = 0, a2 = 0, a3 = 0;
#pragma unroll
    for (int f = 0; f < 16; ++f) {
      float w0 = c1w[(i * 16 + f) * 3 + 0];
      float w1 = c1w[(i * 16 + f) * 3 + 1];
      float w2 = c1w[(i * 16 + f) * 3 + 2];
      float h1 = fmaf(w0, s0, fmaf(w1, s1, w2 * s2));
      a0 = fmaf(c2w[(i * 4 + 0) * 16 + f], h1, a0);
      a1 = fmaf(c2w[(i * 4 + 1) * 16 + f], h1, a1);
      a2 = fmaf(c2w[(i * 4 + 2) * 16 + f], h1, a2);
      a3 = fmaf(c2w[(i * 4 + 3) * 16 + f], h1, a3);
    }
    hn[t] = fmaxf(fmaxf(a0, a1), fmaxf(a2, a3));
  }
  __syncthreads();

  // ---- l1: 25 outputs, column-major write A1t[i*25+k][b] ----
  if (t < 25) {
    float acc = l1b[i * 25 + t];
    const float* w = l1w + ((size_t)i * 25 + t) * NE;
#pragma unroll 5
    for (int m = 0; m < NE; ++m) acc = fmaf(w[m], hn[m], acc);
    A1t[((size_t)(i * 25 + t)) * B + b] = acc;
  }
}

// ---------------------------------------------------------------------------
// KB: bn1 (redundant per-block batch stats from L2) + l2(25x25)+relu + fc1.
// One block per b, 256 threads. Yt layout [100][B] for KE's coalesced stats.
// ---------------------------------------------------------------------------
__global__ __launch_bounds__(256) void k_tail1(
    const float* __restrict__ A1t, const float* __restrict__ g1,
    const float* __restrict__ b1, const float* __restrict__ l2w,
    const float* __restrict__ l2b, const float* __restrict__ fc1w,
    const float* __restrict__ fc1b, float* __restrict__ Yt) {
  int b = blockIdx.x;
  int t = threadIdx.x;
  __shared__ float xin[200];
  __shared__ float Xl[200];

  if (t < 200) {
    const float4* col = (const float4*)(A1t + (size_t)t * B);
    float4 s4 = {0, 0, 0, 0}, q4 = {0, 0, 0, 0};
#pragma unroll
    for (int u = 0; u < B / 4; ++u) {
      float4 v = col[u];
      s4.x += v.x; s4.y += v.y; s4.z += v.z; s4.w += v.w;
      q4.x = fmaf(v.x, v.x, q4.x); q4.y = fmaf(v.y, v.y, q4.y);
      q4.z = fmaf(v.z, v.z, q4.z); q4.w = fmaf(v.w, v.w, q4.w);
    }
    float s = (s4.x + s4.y) + (s4.z + s4.w);
    float q = (q4.x + q4.y) + (q4.z + q4.w);
    float m = s * (1.0f / B);
    float var = q * (1.0f / B) - m * m;
    float r = rsqrtf(var + EPS);
    float v = A1t[(size_t)t * B + b];
    xin[t] = (v - m) * r * g1[t] + b1[t];
  }
  __syncthreads();
  if (t < 200) {
    int i = t / 25;
    float acc = l2b[t];
    const float* w = l2w + (size_t)t * 25;
    const float* x = xin + i * 25;
#pragma unroll
    for (int jj = 0; jj < 25; ++jj) acc = fmaf(w[jj], x[jj], acc);
    Xl[t] = fmaxf(acc, 0.0f);
  }
  __syncthreads();
  if (t < 100) {
    float acc = fc1b[t];
    const float* w = fc1w + (size_t)t * 200;
#pragma unroll 8
    for (int q = 0; q < 200; ++q) acc = fmaf(w[q], Xl[q], acc);
    Yt[(size_t)t * B + b] = acc;
  }
}

// ---------------------------------------------------------------------------
// KC: bn2 (redundant per-block stats) + fc2 -> out[B,70]
// ---------------------------------------------------------------------------
__global__ __launch_bounds__(128) void k_tail2(
    const float* __restrict__ Yt, const float* __restrict__ g2,
    const float* __restrict__ b2, const float* __restrict__ fc2w,
    const float* __restrict__ fc2b, float* __restrict__ out) {
  int b = blockIdx.x;
  int t = threadIdx.x;
  __shared__ float yin[100];
  if (t < 100) {
    const float4* col = (const float4*)(Yt + (size_t)t * B);
    float4 s4 = {0, 0, 0, 0}, q4 = {0, 0, 0, 0};
#pragma unroll
    for (int u = 0; u < B / 4; ++u) {
      float4 v = col[u];
      s4.x += v.x; s4.y += v.y; s4.z += v.z; s4.w += v.w;
      q4.x = fmaf(v.x, v.x, q4.x); q4.y = fmaf(v.y, v.y, q4.y);
      q4.z = fmaf(v.z, v.z, q4.z); q4.w = fmaf(v.w, v.w, q4.w);
    }
    float s = (s4.x + s4.y) + (s4.z + s4.w);
    float q = (q4.x + q4.y) + (q4.z + q4.w);
    float m = s * (1.0f / B);
    float var = q * (1.0f / B) - m * m;
    float r = rsqrtf(var + EPS);
    float v = Yt[(size_t)t * B + b];
    yin[t] = (v - m) * r * g2[t] + b2[t];
  }
  __syncthreads();
  if (t < 70) {
    float acc = fc2b[t];
    const float* w = fc2w + (size_t)t * 100;
#pragma unroll 4
    for (int m = 0; m < 100; ++m) acc = fmaf(w[m], yin[m], acc);
    out[(size_t)b * 70 + t] = acc;
  }
}

// ---------------------------------------------------------------------------
extern "C" void kernel_launch(void* const* d_in, const int* in_sizes, int n_in,
                              void* d_out, int out_size, void* d_ws, size_t ws_size,
                              hipStream_t stream) {
  const float2* pts2   = (const float2*)d_in[0];
  const int*   lengths = (const int*)d_in[1];
  const float* centers = (const float*)d_in[2];
  const float* sharp   = (const float*)d_in[3];
  const float* c1w     = (const float*)d_in[4];
  const float* c2w     = (const float*)d_in[5];
  const float* l1w     = (const float*)d_in[6];
  const float* l1b     = (const float*)d_in[7];
  const float* bn1g    = (const float*)d_in[8];
  const float* bn1b    = (const float*)d_in[9];
  const float* l2w     = (const float*)d_in[10];
  const float* l2b     = (const float*)d_in[11];
  const float* fc1w    = (const float*)d_in[12];
  const float* fc1b    = (const float*)d_in[13];
  const float* fbn_g   = (const float*)d_in[14];
  const float* fbn_b   = (const float*)d_in[15];
  const float* fc2w    = (const float*)d_in[16];
  const float* fc2b    = (const float*)d_in[17];
  float* out = (float*)d_out;

  float* A1t = (float*)d_ws;          // [200][128]
  float* Yt  = A1t + 200 * B;         // [100][128]

  k_structure<<<dim3(V * B), dim3(256), 0, stream>>>(
      pts2, lengths, centers, sharp, c1w, c2w, l1w, l1b, A1t);
  k_tail1<<<dim3(B), dim3(256), 0, stream>>>(
      A1t, bn1g, bn1b, l2w, l2b, fc1w, fc1b, Yt);
  k_tail2<<<dim3(B), dim3(128), 0, stream>>>(
      Yt, fbn_g, fbn_b, fc2w, fc2b, out);
}

// Round 4
// 45.355 us; speedup vs baseline: 1.4286x; 1.0125x over previous
//
#include <hip/hip_runtime.h>
#include <math.h>

#define V 8
#define B 128
#define P 512
#define NE 75

static constexpr float NU = 0.1f;
static constexpr float EPS = 1e-5f;
static constexpr float INV_SQRT2 = 0.70710678118654752440f;
static constexpr float L2E = 1.4426950408889634f;  // log2(e)

typedef float v4f __attribute__((ext_vector_type(4)));

__device__ __forceinline__ float fast_exp2(float x) {
#if __has_builtin(__builtin_amdgcn_exp2f)
  return __builtin_amdgcn_exp2f(x);
#else
  return exp2f(x);
#endif
}

__device__ __forceinline__ v4f v4fma(v4f a, v4f b, v4f c) {
#if __has_builtin(__builtin_elementwise_fma)
  return __builtin_elementwise_fma(a, b, c);
#else
  v4f r;
  r.x = fmaf(a.x, b.x, c.x); r.y = fmaf(a.y, b.y, c.y);
  r.z = fmaf(a.z, b.z, c.z); r.w = fmaf(a.w, b.w, c.w);
  return r;
#endif
}

// ---------------------------------------------------------------------------
// KA (hot, fused): transform + masked Gaussian structure sums + conv1d(3->16)
//                  -> conv1d(16->4) -> channel-max -> l1(75->25)
// One block per (i,b), 256 threads (225 active as (j,n)).
// Masked points staged as 1e9 -> arg ~ -1.2e19 -> exp2 -> 0 exactly, which
// makes the hot loop's trip count purely a wave-uniform scalar (no per-lane
// bounds, no exec-mask churn): wave w covers a known subset of directions,
// trip_w = roundup8(max length of those directions).
// Hot loop per 8 points: 8 ds_read_b128 (broadcast) + 16 v_pk_fma + 8 exp2
// + 8 add.
// ---------------------------------------------------------------------------
__global__ __launch_bounds__(256, 4) void k_structure(
    const float2* __restrict__ pts2,      // [V,B,P] (birth,death)
    const int* __restrict__ lengths,      // [V,B]
    const float* __restrict__ centers,    // [V,NE,2] (transformed)
    const float* __restrict__ sharp,      // [V,NE,2]
    const float* __restrict__ c1w,        // [V,16,3]
    const float* __restrict__ c2w,        // [V,4,16]
    const float* __restrict__ l1w,        // [V,25,NE]
    const float* __restrict__ l1b,        // [V,25]
    float* __restrict__ A1t) {            // [V*25][B]
  int i = blockIdx.x >> 7;
  int b = blockIdx.x & 127;
  int t = threadIdx.x;

  __shared__ float sS[3][P], sY[3][P], sS2[3][P], sY2[3][P];  // 24 KB SoA
  __shared__ float slb[3][NE];
  __shared__ float hn[NE];

  int d0 = (i + V - 1) & (V - 1), d1 = i, d2 = (i + 1) & (V - 1);
  int len0 = lengths[d0 * B + b];
  int len1 = lengths[d1 * B + b];
  int len2 = lengths[d2 * B + b];

  // ---- staging: load+transform 3 directions x 512 points ----
  for (int u = t; u < 3 * P; u += 256) {
    int jj = u >> 9;
    int pp = u & (P - 1);
    int d   = (jj == 0) ? d0 : (jj == 1) ? d1 : d2;
    int len = (jj == 0) ? len0 : (jj == 1) ? len1 : len2;
    float2 q = pts2[((size_t)d * B + b) * P + pp];
    float s = (q.x + q.y) * INV_SQRT2;
    float y = (q.y - q.x) * INV_SQRT2;
    if (y <= NU) y = __logf(fmaxf(y, 1e-12f) * 10.0f) + NU;
    if (pp >= len) { s = 1e9f; y = 1e9f; }
    sS[jj][pp] = s;
    sY[jj][pp] = y;
    sS2[jj][pp] = s * s;
    sY2[jj][pp] = y * y;
  }

  // ---- (j,n) mapping: 225 active lanes; dummies do harmless j=2 work ----
  int j = (t >= 150) ? 2 : (t >= 75 ? 1 : 0);
  int n = t - j * 75;
  bool active = (t < 225);
  if (!active) { j = 2; n = 74; }

  int ci = (i * NE + n) * 2;
  float a  = sharp[ci],   c  = sharp[ci + 1];
  float cs = centers[ci], cy = centers[ci + 1];
  float nA = -a * L2E;
  float nC = -c * L2E;
  float Bsc = 2.0f * a * cs * L2E;
  float Byc = 2.0f * c * cy * L2E;
  float nD = -(a * cs * cs + c * cy * cy) * L2E;
  v4f nA4 = {nA, nA, nA, nA}, nC4 = {nC, nC, nC, nC};
  v4f Bs4 = {Bsc, Bsc, Bsc, Bsc}, By4 = {Byc, Byc, Byc, Byc};
  v4f nD4 = {nD, nD, nD, nD};

  // wave-uniform trip count (scalar loop, no per-lane bounds)
  int w = t >> 6;
  int mx = (w == 0) ? len0
         : (w == 1) ? max(len0, len1)
         : (w == 2) ? max(len1, len2) : len2;
  int trip = (mx + 7) & ~7;

  __syncthreads();

  float ac0 = 0.f, ac1 = 0.f, ac2 = 0.f, ac3 = 0.f;
  float ac4 = 0.f, ac5 = 0.f, ac6 = 0.f, ac7 = 0.f;
  for (int p = 0; p < trip; p += 8) {
    v4f Sa = *(const v4f*)&sS[j][p],  Sb = *(const v4f*)&sS[j][p + 4];
    v4f Ya = *(const v4f*)&sY[j][p],  Yb = *(const v4f*)&sY[j][p + 4];
    v4f Qa = *(const v4f*)&sS2[j][p], Qb = *(const v4f*)&sS2[j][p + 4];
    v4f Ra = *(const v4f*)&sY2[j][p], Rb = *(const v4f*)&sY2[j][p + 4];
    v4f argA = v4fma(Qa, nA4, v4fma(Ra, nC4, v4fma(Sa, Bs4, v4fma(Ya, By4, nD4))));
    v4f argB = v4fma(Qb, nA4, v4fma(Rb, nC4, v4fma(Sb, Bs4, v4fma(Yb, By4, nD4))));
    ac0 += fast_exp2(argA.x);
    ac1 += fast_exp2(argA.y);
    ac2 += fast_exp2(argA.z);
    ac3 += fast_exp2(argA.w);
    ac4 += fast_exp2(argB.x);
    ac5 += fast_exp2(argB.y);
    ac6 += fast_exp2(argB.z);
    ac7 += fast_exp2(argB.w);
  }
  float accv = ((ac0 + ac1) + (ac2 + ac3)) + ((ac4 + ac5) + (ac6 + ac7));

  if (active) slb[j][n] = accv;
  __syncthreads();

  // ---- head: conv1(3->16) -> conv2(16->4) -> channel-max ----
  if (t < NE) {
    float s0 = slb[0][t], s1 = slb[1][t], s2 = slb[2][t];
    float a0 = 0, a1 = 0, a2 = 0, a3 = 0;
#pragma unroll
    for (int f = 0; f < 16; ++f) {
      float w0 = c1w[(i * 16 + f) * 3 + 0];
      float w1 = c1w[(i * 16 + f) * 3 + 1];
      float w2 = c1w[(i * 16 + f) * 3 + 2];
      float h1 = fmaf(w0, s0, fmaf(w1, s1, w2 * s2));
      a0 = fmaf(c2w[(i * 4 + 0) * 16 + f], h1, a0);
      a1 = fmaf(c2w[(i * 4 + 1) * 16 + f], h1, a1);
      a2 = fmaf(c2w[(i * 4 + 2) * 16 + f], h1, a2);
      a3 = fmaf(c2w[(i * 4 + 3) * 16 + f], h1, a3);
    }
    hn[t] = fmaxf(fmaxf(a0, a1), fmaxf(a2, a3));
  }
  __syncthreads();

  // ---- l1: 25 outputs -> A1t[i*25+k][b] (column layout for tail stats) ----
  if (t < 25) {
    float acc = l1b[i * 25 + t];
    const float* wgt = l1w + ((size_t)i * 25 + t) * NE;
#pragma unroll 5
    for (int m = 0; m < NE; ++m) acc = fmaf(wgt[m], hn[m], acc);
    A1t[((size_t)(i * 25 + t)) * B + b] = acc;
  }
}

// ---------------------------------------------------------------------------
// KB: bn1 (redundant per-block batch stats from L2) + l2(25x25)+relu + fc1.
// One block per b, 256 threads. Yt layout [100][B].
// ---------------------------------------------------------------------------
__global__ __launch_bounds__(256) void k_tail1(
    const float* __restrict__ A1t, const float* __restrict__ g1,
    const float* __restrict__ b1, const float* __restrict__ l2w,
    const float* __restrict__ l2b, const float* __restrict__ fc1w,
    const float* __restrict__ fc1b, float* __restrict__ Yt) {
  int b = blockIdx.x;
  int t = threadIdx.x;
  __shared__ float xin[200];
  __shared__ float Xl[200];

  if (t < 200) {
    const float4* col = (const float4*)(A1t + (size_t)t * B);
    float4 s4 = {0, 0, 0, 0}, q4 = {0, 0, 0, 0};
#pragma unroll
    for (int u = 0; u < B / 4; ++u) {
      float4 v = col[u];
      s4.x += v.x; s4.y += v.y; s4.z += v.z; s4.w += v.w;
      q4.x = fmaf(v.x, v.x, q4.x); q4.y = fmaf(v.y, v.y, q4.y);
      q4.z = fmaf(v.z, v.z, q4.z); q4.w = fmaf(v.w, v.w, q4.w);
    }
    float s = (s4.x + s4.y) + (s4.z + s4.w);
    float q = (q4.x + q4.y) + (q4.z + q4.w);
    float m = s * (1.0f / B);
    float var = q * (1.0f / B) - m * m;
    float r = rsqrtf(var + EPS);
    float v = A1t[(size_t)t * B + b];
    xin[t] = (v - m) * r * g1[t] + b1[t];
  }
  __syncthreads();
  if (t < 200) {
    int i = t / 25;
    float acc = l2b[t];
    const float* w = l2w + (size_t)t * 25;
    const float* x = xin + i * 25;
#pragma unroll
    for (int jj = 0; jj < 25; ++jj) acc = fmaf(w[jj], x[jj], acc);
    Xl[t] = fmaxf(acc, 0.0f);
  }
  __syncthreads();
  if (t < 100) {
    float acc = fc1b[t];
    const float* w = fc1w + (size_t)t * 200;
#pragma unroll 8
    for (int q = 0; q < 200; ++q) acc = fmaf(w[q], Xl[q], acc);
    Yt[(size_t)t * B + b] = acc;
  }
}

// ---------------------------------------------------------------------------
// KC: bn2 (redundant per-block stats) + fc2 -> out[B,70]
// ---------------------------------------------------------------------------
__global__ __launch_bounds__(128) void k_tail2(
    const float* __restrict__ Yt, const float* __restrict__ g2,
    const float* __restrict__ b2, const float* __restrict__ fc2w,
    const float* __restrict__ fc2b, float* __restrict__ out) {
  int b = blockIdx.x;
  int t = threadIdx.x;
  __shared__ float yin[100];
  if (t < 100) {
    const float4* col = (const float4*)(Yt + (size_t)t * B);
    float4 s4 = {0, 0, 0, 0}, q4 = {0, 0, 0, 0};
#pragma unroll
    for (int u = 0; u < B / 4; ++u) {
      float4 v = col[u];
      s4.x += v.x; s4.y += v.y; s4.z += v.z; s4.w += v.w;
      q4.x = fmaf(v.x, v.x, q4.x); q4.y = fmaf(v.y, v.y, q4.y);
      q4.z = fmaf(v.z, v.z, q4.z); q4.w = fmaf(v.w, v.w, q4.w);
    }
    float s = (s4.x + s4.y) + (s4.z + s4.w);
    float q = (q4.x + q4.y) + (q4.z + q4.w);
    float m = s * (1.0f / B);
    float var = q * (1.0f / B) - m * m;
    float r = rsqrtf(var + EPS);
    float v = Yt[(size_t)t * B + b];
    yin[t] = (v - m) * r * g2[t] + b2[t];
  }
  __syncthreads();
  if (t < 70) {
    float acc = fc2b[t];
    const float* w = fc2w + (size_t)t * 100;
#pragma unroll 4
    for (int m = 0; m < 100; ++m) acc = fmaf(w[m], yin[m], acc);
    out[(size_t)b * 70 + t] = acc;
  }
}

// ---------------------------------------------------------------------------
extern "C" void kernel_launch(void* const* d_in, const int* in_sizes, int n_in,
                              void* d_out, int out_size, void* d_ws, size_t ws_size,
                              hipStream_t stream) {
  const float2* pts2   = (const float2*)d_in[0];
  const int*   lengths = (const int*)d_in[1];
  const float* centers = (const float*)d_in[2];
  const float* sharp   = (const float*)d_in[3];
  const float* c1w     = (const float*)d_in[4];
  const float* c2w     = (const float*)d_in[5];
  const float* l1w     = (const float*)d_in[6];
  const float* l1b     = (const float*)d_in[7];
  const float* bn1g    = (const float*)d_in[8];
  const float* bn1b    = (const float*)d_in[9];
  const float* l2w     = (const float*)d_in[10];
  const float* l2b     = (const float*)d_in[11];
  const float* fc1w    = (const float*)d_in[12];
  const float* fc1b    = (const float*)d_in[13];
  const float* fbn_g   = (const float*)d_in[14];
  const float* fbn_b   = (const float*)d_in[15];
  const float* fc2w    = (const float*)d_in[16];
  const float* fc2b    = (const float*)d_in[17];
  float* out = (float*)d_out;

  float* A1t = (float*)d_ws;          // [200][128]
  float* Yt  = A1t + 200 * B;         // [100][128]

  k_structure<<<dim3(V * B), dim3(256), 0, stream>>>(
      pts2, lengths, centers, sharp, c1w, c2w, l1w, l1b, A1t);
  k_tail1<<<dim3(B), dim3(256), 0, stream>>>(
      A1t, bn1g, bn1b, l2w, l2b, fc1w, fc1b, Yt);
  k_tail2<<<dim3(B), dim3(128), 0, stream>>>(
      Yt, fbn_g, fbn_b, fc2w, fc2b, out);
}